// Round 1
// baseline (7092.020 us; speedup 1.0000x reference)
//
#include <hip/hip_runtime.h>
#include <hip/hip_cooperative_groups.h>

namespace cg = cooperative_groups;

#define STEPS 96
#define HDIM 4096
#define IDIM 1024
#define BLOCKS 256
#define THREADS 512
#define WAVES (THREADS / 64)
#define ROWS_PER_BLOCK (HDIM / BLOCKS)      // 16
#define ROWS_PER_WAVE (ROWS_PER_BLOCK / WAVES)  // 2

// ---------------- weight loaders (8 contiguous elems -> f32[8]) ----------------
__device__ inline void wload8(const unsigned short* __restrict__ w, float* o) {
  uint4 u = *reinterpret_cast<const uint4*>(w);  // 8 bf16
  o[0] = __uint_as_float(u.x << 16);
  o[1] = __uint_as_float(u.x & 0xffff0000u);
  o[2] = __uint_as_float(u.y << 16);
  o[3] = __uint_as_float(u.y & 0xffff0000u);
  o[4] = __uint_as_float(u.z << 16);
  o[5] = __uint_as_float(u.z & 0xffff0000u);
  o[6] = __uint_as_float(u.w << 16);
  o[7] = __uint_as_float(u.w & 0xffff0000u);
}
__device__ inline void wload8(const float* __restrict__ w, float* o) {
  float4 a = *reinterpret_cast<const float4*>(w);
  float4 b = *reinterpret_cast<const float4*>(w + 4);
  o[0] = a.x; o[1] = a.y; o[2] = a.z; o[3] = a.w;
  o[4] = b.x; o[5] = b.y; o[6] = b.z; o[7] = b.w;
}

// one wave computes a partial dot over NC columns; lane-strided 8-elem chunks
template <typename WT, int NC>
__device__ inline float dotp(const WT* __restrict__ w, const float* v, int lane) {
  float acc = 0.f;
#pragma unroll
  for (int it = 0; it < NC / 512; ++it) {
    const int base = it * 512 + lane * 8;
    float wf[8];
    wload8(w + base, wf);
    const float* vp = v + base;
#pragma unroll
    for (int k = 0; k < 8; ++k) acc += wf[k] * vp[k];
  }
  return acc;
}

__device__ inline float wave_reduce(float v) {
#pragma unroll
  for (int off = 32; off > 0; off >>= 1) v += __shfl_xor(v, off);
  return v;
}

template <typename WT>
struct Params {
  const WT *Wih0, *Whh0, *Wih1, *Whh1, *Wfc;
  const float *x, *b_ih0, *b_hh0, *b_ih1, *b_hh1, *b_fc;
  float* h0buf;  // [2][HDIM]
  float* h1buf;  // [2][HDIM]
  float* out;    // [STEPS]
};

template <typename WT>
__global__ void __launch_bounds__(THREADS)
rnn_kernel(Params<WT> p) {
  __shared__ float win[IDIM + STEPS];  // sliding window, no wraparound needed
  __shared__ float vecA[HDIM];
  __shared__ float vecB[HDIM];
  __shared__ float red[WAVES];

  cg::grid_group grid = cg::this_grid();
  const int tid = threadIdx.x;
  const int lane = tid & 63;
  const int wv = tid >> 6;
  const int blk = blockIdx.x;

  // init private window copy from x
  for (int i = tid; i < IDIM; i += THREADS) win[i] = p.x[i];

  for (int t = 0; t < STEPS; ++t) {
    const int par = t & 1;
    float* h0_new = p.h0buf + par * HDIM;
    const float* h0_old = p.h0buf + (par ^ 1) * HDIM;
    float* h1_new = p.h1buf + par * HDIM;
    const float* h1_old = p.h1buf + (par ^ 1) * HDIM;

    // ---- phase 1: h0 = tanh(Wih0 @ win + Whh0 @ h0_old + b) ----
    if (t == 0) {
      for (int i = tid; i < HDIM; i += THREADS) vecA[i] = 0.f;
    } else {
      for (int i = tid * 4; i < HDIM; i += THREADS * 4)
        *reinterpret_cast<float4*>(vecA + i) = *reinterpret_cast<const float4*>(h0_old + i);
    }
    __syncthreads();
#pragma unroll
    for (int r = 0; r < ROWS_PER_WAVE; ++r) {
      const int row = blk * ROWS_PER_BLOCK + wv * ROWS_PER_WAVE + r;
      float acc = dotp<WT, IDIM>(p.Wih0 + (size_t)row * IDIM, win + t, lane) +
                  dotp<WT, HDIM>(p.Whh0 + (size_t)row * HDIM, vecA, lane);
      acc = wave_reduce(acc);
      if (lane == 0) h0_new[row] = tanhf(acc + p.b_ih0[row] + p.b_hh0[row]);
    }
    grid.sync();

    // ---- phase 2: h1 = tanh(Wih1 @ h0 + Whh1 @ h1_old + b) ----
    for (int i = tid * 4; i < HDIM; i += THREADS * 4)
      *reinterpret_cast<float4*>(vecA + i) = *reinterpret_cast<const float4*>(h0_new + i);
    if (t == 0) {
      for (int i = tid; i < HDIM; i += THREADS) vecB[i] = 0.f;
    } else {
      for (int i = tid * 4; i < HDIM; i += THREADS * 4)
        *reinterpret_cast<float4*>(vecB + i) = *reinterpret_cast<const float4*>(h1_old + i);
    }
    __syncthreads();
#pragma unroll
    for (int r = 0; r < ROWS_PER_WAVE; ++r) {
      const int row = blk * ROWS_PER_BLOCK + wv * ROWS_PER_WAVE + r;
      float acc = dotp<WT, HDIM>(p.Wih1 + (size_t)row * HDIM, vecA, lane) +
                  dotp<WT, HDIM>(p.Whh1 + (size_t)row * HDIM, vecB, lane);
      acc = wave_reduce(acc);
      if (lane == 0) h1_new[row] = tanhf(acc + p.b_ih1[row] + p.b_hh1[row]);
    }
    grid.sync();

    // ---- phase 3: y = Wfc @ h1 + b_fc ; append to private window ----
    {
      const int base = tid * 8;  // THREADS*8 == HDIM
      float wf[8];
      wload8(p.Wfc + base, wf);
      float4 ha = *reinterpret_cast<const float4*>(h1_new + base);
      float4 hb = *reinterpret_cast<const float4*>(h1_new + base + 4);
      float part = wf[0] * ha.x + wf[1] * ha.y + wf[2] * ha.z + wf[3] * ha.w +
                   wf[4] * hb.x + wf[5] * hb.y + wf[6] * hb.z + wf[7] * hb.w;
      part = wave_reduce(part);
      if (lane == 0) red[wv] = part;
    }
    __syncthreads();
    if (tid == 0) {
      float y = p.b_fc[0];
#pragma unroll
      for (int i = 0; i < WAVES; ++i) y += red[i];
      win[IDIM + t] = y;
      if (blk == 0) p.out[t] = y;
    }
    __syncthreads();
  }
}

// ---------------- f32 -> bf16 (RNE) conversion ----------------
__device__ inline unsigned short f2bf(float f) {
  unsigned int u = __float_as_uint(f);
  u += 0x7fffu + ((u >> 16) & 1u);
  return (unsigned short)(u >> 16);
}

__global__ void cvt_kernel(const float* __restrict__ in, unsigned short* __restrict__ out, int n4) {
  int i = blockIdx.x * blockDim.x + threadIdx.x;
  const int stride = gridDim.x * blockDim.x;
  for (; i < n4; i += stride) {
    float4 f = reinterpret_cast<const float4*>(in)[i];
    ushort4 o;
    o.x = f2bf(f.x); o.y = f2bf(f.y); o.z = f2bf(f.z); o.w = f2bf(f.w);
    reinterpret_cast<ushort4*>(out)[i] = o;
  }
}

extern "C" void kernel_launch(void* const* d_in, const int* in_sizes, int n_in,
                              void* d_out, int out_size, void* d_ws, size_t ws_size,
                              hipStream_t stream) {
  const float* x = (const float*)d_in[0];
  const float* Wih0 = (const float*)d_in[1];
  const float* bih0 = (const float*)d_in[2];
  const float* Whh0 = (const float*)d_in[3];
  const float* bhh0 = (const float*)d_in[4];
  const float* Wih1 = (const float*)d_in[5];
  const float* bih1 = (const float*)d_in[6];
  const float* Whh1 = (const float*)d_in[7];
  const float* bhh1 = (const float*)d_in[8];
  const float* Wfc = (const float*)d_in[9];
  const float* bfc = (const float*)d_in[10];
  float* out = (float*)d_out;

  const size_t nIh0 = (size_t)HDIM * IDIM;
  const size_t nHh = (size_t)HDIM * HDIM;
  const size_t nFc = HDIM;
  const size_t bfBytes = (nIh0 + 3 * nHh + nFc) * 2;  // ~109 MB
  const size_t hBytes = 4 * (size_t)HDIM * 4;          // 64 KB

  if (ws_size >= bfBytes + hBytes) {
    // bf16 path: convert weights into workspace
    unsigned short* wih0 = (unsigned short*)d_ws;
    unsigned short* whh0 = wih0 + nIh0;
    unsigned short* wih1 = whh0 + nHh;
    unsigned short* whh1 = wih1 + nHh;
    unsigned short* wfc = whh1 + nHh;
    float* hbuf = (float*)((char*)d_ws + bfBytes);

    cvt_kernel<<<4096, 256, 0, stream>>>(Wih0, wih0, (int)(nIh0 / 4));
    cvt_kernel<<<8192, 256, 0, stream>>>(Whh0, whh0, (int)(nHh / 4));
    cvt_kernel<<<8192, 256, 0, stream>>>(Wih1, wih1, (int)(nHh / 4));
    cvt_kernel<<<8192, 256, 0, stream>>>(Whh1, whh1, (int)(nHh / 4));
    cvt_kernel<<<8, 128, 0, stream>>>(Wfc, wfc, (int)(nFc / 4));

    Params<unsigned short> p;
    p.Wih0 = wih0; p.Whh0 = whh0; p.Wih1 = wih1; p.Whh1 = whh1; p.Wfc = wfc;
    p.x = x; p.b_ih0 = bih0; p.b_hh0 = bhh0; p.b_ih1 = bih1; p.b_hh1 = bhh1; p.b_fc = bfc;
    p.h0buf = hbuf; p.h1buf = hbuf + 2 * HDIM; p.out = out;

    void* args[] = {&p};
    hipLaunchCooperativeKernel(reinterpret_cast<void*>(&rnn_kernel<unsigned short>),
                               dim3(BLOCKS), dim3(THREADS), args, 0, stream);
  } else {
    // fallback: f32 weights straight from inputs; only h buffers in ws
    Params<float> p;
    p.Wih0 = Wih0; p.Whh0 = Whh0; p.Wih1 = Wih1; p.Whh1 = Whh1; p.Wfc = Wfc;
    p.x = x; p.b_ih0 = bih0; p.b_hh0 = bhh0; p.b_ih1 = bih1; p.b_hh1 = bhh1; p.b_fc = bfc;
    float* hbuf = (float*)d_ws;
    p.h0buf = hbuf; p.h1buf = hbuf + 2 * HDIM; p.out = out;

    void* args[] = {&p};
    hipLaunchCooperativeKernel(reinterpret_cast<void*>(&rnn_kernel<float>),
                               dim3(BLOCKS), dim3(THREADS), args, 0, stream);
  }
}

// Round 2
// 3924.224 us; speedup vs baseline: 1.8072x; 1.8072x over previous
//
#include <hip/hip_runtime.h>

#define STEPS 96
#define HDIM 4096
#define IDIM 1024
#define BLOCKS 256
#define THREADS 1024
#define WAVES (THREADS / 64)              // 16
#define ROWS_PER_BLOCK (HDIM / BLOCKS)    // 16 == WAVES -> 1 row per wave per phase

// ---------------- weight loaders ----------------
__device__ inline void wload8(const unsigned short* __restrict__ w, float* o) {
  uint4 u = *reinterpret_cast<const uint4*>(w);  // 8 bf16
  o[0] = __uint_as_float(u.x << 16);
  o[1] = __uint_as_float(u.x & 0xffff0000u);
  o[2] = __uint_as_float(u.y << 16);
  o[3] = __uint_as_float(u.y & 0xffff0000u);
  o[4] = __uint_as_float(u.z << 16);
  o[5] = __uint_as_float(u.z & 0xffff0000u);
  o[6] = __uint_as_float(u.w << 16);
  o[7] = __uint_as_float(u.w & 0xffff0000u);
}
__device__ inline void wload8(const float* __restrict__ w, float* o) {
  float4 a = *reinterpret_cast<const float4*>(w);
  float4 b = *reinterpret_cast<const float4*>(w + 4);
  o[0] = a.x; o[1] = a.y; o[2] = a.z; o[3] = a.w;
  o[4] = b.x; o[5] = b.y; o[6] = b.z; o[7] = b.w;
}
__device__ inline void wload4(const unsigned short* __restrict__ w, float* o) {
  uint2 u = *reinterpret_cast<const uint2*>(w);  // 4 bf16
  o[0] = __uint_as_float(u.x << 16);
  o[1] = __uint_as_float(u.x & 0xffff0000u);
  o[2] = __uint_as_float(u.y << 16);
  o[3] = __uint_as_float(u.y & 0xffff0000u);
}
__device__ inline void wload4(const float* __restrict__ w, float* o) {
  float4 f = *reinterpret_cast<const float4*>(w);
  o[0] = f.x; o[1] = f.y; o[2] = f.z; o[3] = f.w;
}

// dot over NC cols, v in GLOBAL memory (16B-aligned), lane-strided 8-elem chunks
template <typename WT, int NC>
__device__ inline float dot_gh(const WT* __restrict__ w, const float* __restrict__ v, int lane) {
  float acc = 0.f;
#pragma unroll
  for (int it = 0; it < NC / 512; ++it) {
    const int base = it * 512 + lane * 8;
    float wf[8];
    wload8(w + base, wf);
    float4 a = *reinterpret_cast<const float4*>(v + base);
    float4 b = *reinterpret_cast<const float4*>(v + base + 4);
    acc += wf[0] * a.x + wf[1] * a.y + wf[2] * a.z + wf[3] * a.w +
           wf[4] * b.x + wf[5] * b.y + wf[6] * b.z + wf[7] * b.w;
  }
  return acc;
}

// dot over IDIM cols, v in LDS (unaligned base, scalar reads)
template <typename WT>
__device__ inline float dot_win(const WT* __restrict__ w, const float* v, int lane) {
  float acc = 0.f;
#pragma unroll
  for (int it = 0; it < IDIM / 512; ++it) {
    const int base = it * 512 + lane * 8;
    float wf[8];
    wload8(w + base, wf);
#pragma unroll
    for (int k = 0; k < 8; ++k) acc += wf[k] * v[base + k];
  }
  return acc;
}

__device__ inline float wave_reduce(float v) {
#pragma unroll
  for (int off = 32; off > 0; off >>= 1) v += __shfl_xor(v, off);
  return v;
}

template <typename WT>
struct Params {
  const WT *Wih0, *Whh0, *Wih1, *Whh1, *Wfc;
  const float *x, *b_ih0, *b_hh0, *b_ih1, *b_hh1, *b_fc;
  float* h0buf;     // [2][HDIM]
  float* h1buf;     // [2][HDIM]
  unsigned* leaf;   // 8 counters, stride 32 u32 (128B)
  unsigned* root;
  unsigned* flag;
  float* out;       // [STEPS]
};

// monotonic hierarchical grid barrier; gen = 1,2,3,...
template <typename WT>
__device__ inline void grid_barrier(const Params<WT>& p, unsigned gen) {
  __syncthreads();
  if (threadIdx.x == 0) {
    __threadfence();  // release this block's global writes
    const int g = blockIdx.x & 7;
    unsigned prev = __hip_atomic_fetch_add(p.leaf + g * 32, 1u, __ATOMIC_RELAXED,
                                           __HIP_MEMORY_SCOPE_AGENT);
    if (prev == gen * (BLOCKS / 8) - 1) {  // last of this group for this gen
      unsigned r = __hip_atomic_fetch_add(p.root, 1u, __ATOMIC_RELAXED,
                                          __HIP_MEMORY_SCOPE_AGENT);
      if (r == gen * 8 - 1) {
        __hip_atomic_store(p.flag, gen, __ATOMIC_RELEASE, __HIP_MEMORY_SCOPE_AGENT);
      }
    }
    while (__hip_atomic_load(p.flag, __ATOMIC_RELAXED, __HIP_MEMORY_SCOPE_AGENT) < gen) {
      __builtin_amdgcn_s_sleep(1);
    }
    __threadfence();  // acquire: invalidate L1/L2 so fresh h is visible
  }
  __syncthreads();
}

template <typename WT>
__global__ void __launch_bounds__(THREADS, 4) rnn_kernel(Params<WT> p) {
  __shared__ float win[IDIM + STEPS];  // sliding window, appended per step
  __shared__ float red[WAVES];

  const int tid = threadIdx.x;
  const int lane = tid & 63;
  const int wv = tid >> 6;
  const int blk = blockIdx.x;
  const int row = blk * ROWS_PER_BLOCK + wv;  // this wave's output row each phase

  for (int i = tid; i < IDIM; i += THREADS) win[i] = p.x[i];
  __syncthreads();

  unsigned gen = 0;
  for (int t = 0; t < STEPS; ++t) {
    const int par = t & 1;
    float* h0n = p.h0buf + par * HDIM;
    const float* h0o = p.h0buf + (par ^ 1) * HDIM;  // zeros at t=0 (memset)
    float* h1n = p.h1buf + par * HDIM;
    const float* h1o = p.h1buf + (par ^ 1) * HDIM;

    // ---- phase 1: h0 = tanh(Wih0 @ win + Whh0 @ h0_old + b) ----
    {
      float acc = dot_win(p.Wih0 + (size_t)row * IDIM, win + t, lane) +
                  dot_gh<WT, HDIM>(p.Whh0 + (size_t)row * HDIM, h0o, lane);
      acc = wave_reduce(acc);
      if (lane == 0) h0n[row] = tanhf(acc + p.b_ih0[row] + p.b_hh0[row]);
    }
    grid_barrier(p, ++gen);

    // ---- phase 2: h1 = tanh(Wih1 @ h0 + Whh1 @ h1_old + b) ----
    {
      float acc = dot_gh<WT, HDIM>(p.Wih1 + (size_t)row * HDIM, h0n, lane) +
                  dot_gh<WT, HDIM>(p.Whh1 + (size_t)row * HDIM, h1o, lane);
      acc = wave_reduce(acc);
      if (lane == 0) h1n[row] = tanhf(acc + p.b_ih1[row] + p.b_hh1[row]);
    }
    grid_barrier(p, ++gen);

    // ---- phase 3: y = Wfc @ h1 + b_fc (redundant per block) ----
    {
      const int base = tid * 4;  // THREADS*4 == HDIM
      float wf[4];
      wload4(p.Wfc + base, wf);
      float4 h = *reinterpret_cast<const float4*>(h1n + base);
      float part = wf[0] * h.x + wf[1] * h.y + wf[2] * h.z + wf[3] * h.w;
      part = wave_reduce(part);
      if (lane == 0) red[wv] = part;
    }
    __syncthreads();
    if (tid == 0) {
      float y = p.b_fc[0];
#pragma unroll
      for (int i = 0; i < WAVES; ++i) y += red[i];
      win[IDIM + t] = y;
      if (blk == 0) p.out[t] = y;
    }
    __syncthreads();
  }
}

// ---------------- f32 -> bf16 (RNE) conversion ----------------
__device__ inline unsigned short f2bf(float f) {
  unsigned int u = __float_as_uint(f);
  u += 0x7fffu + ((u >> 16) & 1u);
  return (unsigned short)(u >> 16);
}

__global__ void cvt_kernel(const float* __restrict__ in, unsigned short* __restrict__ out, int n4) {
  int i = blockIdx.x * blockDim.x + threadIdx.x;
  const int stride = gridDim.x * blockDim.x;
  for (; i < n4; i += stride) {
    float4 f = reinterpret_cast<const float4*>(in)[i];
    ushort4 o;
    o.x = f2bf(f.x); o.y = f2bf(f.y); o.z = f2bf(f.z); o.w = f2bf(f.w);
    reinterpret_cast<ushort4*>(out)[i] = o;
  }
}

extern "C" void kernel_launch(void* const* d_in, const int* in_sizes, int n_in,
                              void* d_out, int out_size, void* d_ws, size_t ws_size,
                              hipStream_t stream) {
  const float* x = (const float*)d_in[0];
  const float* Wih0 = (const float*)d_in[1];
  const float* bih0 = (const float*)d_in[2];
  const float* Whh0 = (const float*)d_in[3];
  const float* bhh0 = (const float*)d_in[4];
  const float* Wih1 = (const float*)d_in[5];
  const float* bih1 = (const float*)d_in[6];
  const float* Whh1 = (const float*)d_in[7];
  const float* bhh1 = (const float*)d_in[8];
  const float* Wfc = (const float*)d_in[9];
  const float* bfc = (const float*)d_in[10];
  float* out = (float*)d_out;

  const size_t nIh0 = (size_t)HDIM * IDIM;
  const size_t nHh = (size_t)HDIM * HDIM;
  const size_t nFc = HDIM;
  const size_t bfBytes = (nIh0 + 3 * nHh + nFc) * 2;  // ~109 MB
  // dynamic region: h buffers (4*HDIM f32) + barrier (8*32 + 32 + 32 u32)
  const size_t hFloats = 4 * (size_t)HDIM;
  const size_t barU32 = 8 * 32 + 32 + 32;
  const size_t dynBytes = hFloats * 4 + barU32 * 4;

  if (ws_size >= bfBytes + dynBytes + 256) {
    unsigned short* wih0 = (unsigned short*)d_ws;
    unsigned short* whh0 = wih0 + nIh0;
    unsigned short* wih1 = whh0 + nHh;
    unsigned short* whh1 = wih1 + nHh;
    unsigned short* wfc = whh1 + nHh;
    char* dyn = (char*)d_ws + ((bfBytes + 255) & ~(size_t)255);
    float* hbuf = (float*)dyn;
    unsigned* bar = (unsigned*)(dyn + hFloats * 4);

    cvt_kernel<<<4096, 256, 0, stream>>>(Wih0, wih0, (int)(nIh0 / 4));
    cvt_kernel<<<8192, 256, 0, stream>>>(Whh0, whh0, (int)(nHh / 4));
    cvt_kernel<<<8192, 256, 0, stream>>>(Wih1, wih1, (int)(nHh / 4));
    cvt_kernel<<<8192, 256, 0, stream>>>(Whh1, whh1, (int)(nHh / 4));
    cvt_kernel<<<8, 128, 0, stream>>>(Wfc, wfc, (int)(nFc / 4));
    hipMemsetAsync(dyn, 0, dynBytes, stream);  // zero h bufs + barrier state

    Params<unsigned short> p;
    p.Wih0 = wih0; p.Whh0 = whh0; p.Wih1 = wih1; p.Whh1 = whh1; p.Wfc = wfc;
    p.x = x; p.b_ih0 = bih0; p.b_hh0 = bhh0; p.b_ih1 = bih1; p.b_hh1 = bhh1; p.b_fc = bfc;
    p.h0buf = hbuf; p.h1buf = hbuf + 2 * HDIM;
    p.leaf = bar; p.root = bar + 8 * 32; p.flag = bar + 8 * 32 + 32;
    p.out = out;

    void* args[] = {&p};
    hipLaunchCooperativeKernel(reinterpret_cast<void*>(&rnn_kernel<unsigned short>),
                               dim3(BLOCKS), dim3(THREADS), args, 0, stream);
  } else {
    // fallback: f32 weights straight from inputs
    char* dyn = (char*)d_ws;
    float* hbuf = (float*)dyn;
    unsigned* bar = (unsigned*)(dyn + hFloats * 4);
    hipMemsetAsync(dyn, 0, dynBytes, stream);

    Params<float> p;
    p.Wih0 = Wih0; p.Whh0 = Whh0; p.Wih1 = Wih1; p.Whh1 = Whh1; p.Wfc = Wfc;
    p.x = x; p.b_ih0 = bih0; p.b_hh0 = bhh0; p.b_ih1 = bih1; p.b_hh1 = bhh1; p.b_fc = bfc;
    p.h0buf = hbuf; p.h1buf = hbuf + 2 * HDIM;
    p.leaf = bar; p.root = bar + 8 * 32; p.flag = bar + 8 * 32 + 32;
    p.out = out;

    void* args[] = {&p};
    hipLaunchCooperativeKernel(reinterpret_cast<void*>(&rnn_kernel<float>),
                               dim3(BLOCKS), dim3(THREADS), args, 0, stream);
  }
}